// Round 1
// baseline (1097.979 us; speedup 1.0000x reference)
//
#include <hip/hip_runtime.h>
#include <math.h>

// Problem constants: B=4, T=2048, E=1024, H*D=1024; R = B*T = 8192 rows.
#define R_ROWS 8192
#define T_SEQ  2048
#define E_DIM  1024

// ---------------------------------------------------------------------------
// Tiled fp32 NT GEMM: C[r,o] = sum_i A[r,i] * W[o,i], M=8192, N=K=1024.
// 64x64 tile, BK=16, 256 threads, 4x4 per thread.
// MODE 0: don't store C; atomicAdd per-row sum of squares into aux (sc_raw).
// MODE 1: plain store C.
// MODE 2: store C * (1/aux[row])  (row-wise softmax denominator fold-in).
// ---------------------------------------------------------------------------
template<int MODE>
__global__ __launch_bounds__(256) void gemm_nt(
    const float* __restrict__ A, const float* __restrict__ W,
    float* __restrict__ C, float* __restrict__ aux)
{
  const int K = 1024;
  __shared__ float As[16][68];  // [k][m], pad 68 keeps float4 alignment + bank spread
  __shared__ float Bs[16][68];  // [k][n]
  const int m0 = blockIdx.y * 64;
  const int n0 = blockIdx.x * 64;
  const int tid = threadIdx.x;
  const int lr = tid >> 2;          // 0..63 tile row for staging
  const int lk = (tid & 3) << 2;    // k offset 0,4,8,12
  const float* Ap = A + (size_t)(m0 + lr) * K + lk;
  const float* Wp = W + (size_t)(n0 + lr) * K + lk;
  const int tt = (tid >> 4) << 2;   // 0..60 (4 rows per thread)
  const int nn = (tid & 15) << 2;   // 0..60 (4 cols per thread)

  float acc[4][4] = {};
  for (int k0 = 0; k0 < K; k0 += 16) {
    const float4 av = *(const float4*)(Ap + k0);
    const float4 wv = *(const float4*)(Wp + k0);
    As[lk+0][lr]=av.x; As[lk+1][lr]=av.y; As[lk+2][lr]=av.z; As[lk+3][lr]=av.w;
    Bs[lk+0][lr]=wv.x; Bs[lk+1][lr]=wv.y; Bs[lk+2][lr]=wv.z; Bs[lk+3][lr]=wv.w;
    __syncthreads();
#pragma unroll
    for (int k = 0; k < 16; ++k) {
      const float4 a4 = *(const float4*)&As[k][tt];
      const float4 b4 = *(const float4*)&Bs[k][nn];
      const float a[4] = {a4.x, a4.y, a4.z, a4.w};
      const float bv[4] = {b4.x, b4.y, b4.z, b4.w};
#pragma unroll
      for (int i = 0; i < 4; ++i)
#pragma unroll
        for (int j = 0; j < 4; ++j)
          acc[i][j] = fmaf(a[i], bv[j], acc[i][j]);
    }
    __syncthreads();
  }

  if constexpr (MODE == 0) {
    __shared__ float red[64][17];
#pragma unroll
    for (int i = 0; i < 4; ++i) {
      const float s = acc[i][0]*acc[i][0] + acc[i][1]*acc[i][1]
                    + acc[i][2]*acc[i][2] + acc[i][3]*acc[i][3];
      red[tt + i][tid & 15] = s;
    }
    __syncthreads();
    if (tid < 64) {
      float s = 0.f;
#pragma unroll
      for (int j = 0; j < 16; ++j) s += red[tid][j];
      atomicAdd(&aux[m0 + tid], s);
    }
  } else {
    float scale[4];
    if constexpr (MODE == 2) {
#pragma unroll
      for (int i = 0; i < 4; ++i) scale[i] = 1.0f / aux[m0 + tt + i];
    } else {
#pragma unroll
      for (int i = 0; i < 4; ++i) scale[i] = 1.0f;
    }
#pragma unroll
    for (int i = 0; i < 4; ++i) {
      const float4 o = make_float4(acc[i][0]*scale[i], acc[i][1]*scale[i],
                                   acc[i][2]*scale[i], acc[i][3]*scale[i]);
      *(float4*)&C[(size_t)(m0 + tt + i) * 1024 + n0 + nn] = o;
    }
  }
}

// ---------------------------------------------------------------------------
// Per-batch: sc = sc_raw/32 (sqrt(E)=32), pmax = inclusive prefix max of sc.
// One block of 1024 threads per batch; Hillis-Steele scan over 2048 elems.
// ---------------------------------------------------------------------------
__global__ __launch_bounds__(1024) void scan_max(
    const float* __restrict__ sc_raw, float* __restrict__ sc,
    float* __restrict__ pmax)
{
  const int b = blockIdx.x;
  __shared__ float b0[T_SEQ];
  __shared__ float b1[T_SEQ];
  const int tid = threadIdx.x;
  for (int i = tid; i < T_SEQ; i += 1024) {
    const float v = sc_raw[b*T_SEQ + i] * 0.03125f;  // /32
    b0[i] = v;
    sc[b*T_SEQ + i] = v;
  }
  __syncthreads();
  float* src = b0; float* dst = b1;
  for (int off = 1; off < T_SEQ; off <<= 1) {
    for (int i = tid; i < T_SEQ; i += 1024)
      dst[i] = (i >= off) ? fmaxf(src[i], src[i - off]) : src[i];
    __syncthreads();
    float* tmp = src; src = dst; dst = tmp;
  }
  for (int i = tid; i < T_SEQ; i += 1024) pmax[b*T_SEQ + i] = src[i];
}

// ---------------------------------------------------------------------------
// Fused causal rank-1-score attention:
//   attn[b,t,e] = sum_{s<=t} exp(sc_t*(sc_s - pmax_t)) * val[b,s,e]   (UNnormalized)
//   Z[b,t]     = sum_{s<=t} exp(sc_t*(sc_s - pmax_t))   (stored by e-block 0)
// Grid: (E/64=16, T/64=32, B=4); block 256; 64(t) x 64(e) out tile.
// ---------------------------------------------------------------------------
__global__ __launch_bounds__(256) void attn_fused(
    const float* __restrict__ val, const float* __restrict__ sc,
    const float* __restrict__ pmax, float* __restrict__ attn,
    float* __restrict__ Zout)
{
  const int b  = blockIdx.z;
  const int t0 = blockIdx.y * 64;
  const int e0 = blockIdx.x * 64;
  const int tid = threadIdx.x;
  __shared__ float pT[64][68];   // [s][t] so GEMM reads float4 along t
  __shared__ float vs[64][68];   // [s][e]
  __shared__ float sct[64], pmt[64], scs[64];
  __shared__ float zred[64][17];
  const int tt = (tid >> 4) << 2;
  const int ee = (tid & 15) << 2;

  if (tid < 64) {
    sct[tid] = sc[b*T_SEQ + t0 + tid];
    pmt[tid] = pmax[b*T_SEQ + t0 + tid];
  }

  float acc[4][4] = {};
  float zp[4] = {0.f, 0.f, 0.f, 0.f};
  const int nchunk = blockIdx.y + 1;

  for (int c = 0; c < nchunk; ++c) {
    const int s0 = c * 64;
    // stage val tile (64 s x 64 e)
#pragma unroll
    for (int i = 0; i < 4; ++i) {
      const int slot = tid + i * 256;
      const int r = slot >> 4;
      const int col = (slot & 15) << 2;
      *(float4*)&vs[r][col] =
          *(const float4*)&val[(size_t)(b*T_SEQ + s0 + r) * E_DIM + e0 + col];
    }
    if (tid < 64) scs[tid] = sc[b*T_SEQ + s0 + tid];
    __syncthreads();

    // p generation (each thread: rows tt..tt+3, s-cols ee..ee+3)
#pragma unroll
    for (int i = 0; i < 4; ++i) {
      const float st = sct[tt + i];
      const float pm = pmt[tt + i];
      const int tglob = t0 + tt + i;
#pragma unroll
      for (int j = 0; j < 4; ++j) {
        const int sglob = s0 + ee + j;
        float p = 0.0f;
        if (sglob <= tglob) p = __expf(st * (scs[ee + j] - pm));
        pT[ee + j][tt + i] = p;
        zp[i] += p;
      }
    }
    __syncthreads();

    // acc += P^T-tile * val-tile
#pragma unroll 4
    for (int s = 0; s < 64; ++s) {
      const float4 p4 = *(const float4*)&pT[s][tt];
      const float4 v4 = *(const float4*)&vs[s][ee];
      const float p[4] = {p4.x, p4.y, p4.z, p4.w};
      const float v[4] = {v4.x, v4.y, v4.z, v4.w};
#pragma unroll
      for (int i = 0; i < 4; ++i)
#pragma unroll
        for (int j = 0; j < 4; ++j)
          acc[i][j] = fmaf(p[i], v[j], acc[i][j]);
    }
    __syncthreads();
  }

  // store unnormalized attn (normalization folded into final GEMM)
#pragma unroll
  for (int i = 0; i < 4; ++i) {
    *(float4*)&attn[(size_t)(b*T_SEQ + t0 + tt + i) * E_DIM + e0 + ee] =
        make_float4(acc[i][0], acc[i][1], acc[i][2], acc[i][3]);
  }

  // Z: only one e-block per (b, t-tile) writes
  if (blockIdx.x == 0) {
#pragma unroll
    for (int i = 0; i < 4; ++i) zred[tt + i][tid & 15] = zp[i];
    __syncthreads();
    if (tid < 64) {
      float s = 0.f;
#pragma unroll
      for (int j = 0; j < 16; ++j) s += zred[tid][j];
      Zout[b*T_SEQ + t0 + tid] = s;
    }
  }
}

// ---------------------------------------------------------------------------
extern "C" void kernel_launch(void* const* d_in, const int* in_sizes, int n_in,
                              void* d_out, int out_size, void* d_ws, size_t ws_size,
                              hipStream_t stream) {
  (void)in_sizes; (void)n_in; (void)out_size; (void)ws_size;
  const float* x   = (const float*)d_in[0];
  const float* wj  = (const float*)d_in[1];
  const float* wjv = (const float*)d_in[2];
  const float* wo  = (const float*)d_in[3];
  float* out = (float*)d_out;

  float* val    = (float*)d_ws;                       // 8192*1024 f32 (32 MB)
  float* attn   = val + (size_t)R_ROWS * E_DIM;       // 8192*1024 f32 (32 MB)
  float* sc_raw = attn + (size_t)R_ROWS * E_DIM;      // 8192 f32
  float* sc     = sc_raw + R_ROWS;                    // 8192 f32
  float* pmax   = sc + R_ROWS;                        // 8192 f32
  float* Z      = pmax + R_ROWS;                      // 8192 f32

  hipMemsetAsync(sc_raw, 0, R_ROWS * sizeof(float), stream);

  const dim3 g(16, 128), blk(256);
  // sc_raw[r] = ||x_r @ wj^T||^2  (no echo materialization, GEMM2 eliminated)
  gemm_nt<0><<<g, blk, 0, stream>>>(x, wj, nullptr, sc_raw);
  // val = x @ wjv^T
  gemm_nt<1><<<g, blk, 0, stream>>>(x, wjv, val, nullptr);
  // sc = sc_raw/32 ; pmax = prefix max per batch
  scan_max<<<4, 1024, 0, stream>>>(sc_raw, sc, pmax);
  // unnormalized attention + Z
  attn_fused<<<dim3(16, 32, 4), blk, 0, stream>>>(val, sc, pmax, attn, Z);
  // out = diag(1/Z) * attn @ wo^T
  gemm_nt<2><<<g, blk, 0, stream>>>(attn, wo, out, Z);
}

// Round 2
// 555.549 us; speedup vs baseline: 1.9764x; 1.9764x over previous
//
#include <hip/hip_runtime.h>
#include <math.h>

// B=4, T=2048, E=1024, H*D=1024; R = B*T = 8192.
#define R_ROWS 8192
#define T_SEQ  2048
#define E_DIM  1024

typedef __attribute__((ext_vector_type(8))) short short8;
typedef __attribute__((ext_vector_type(4))) float f32x4;

__device__ __forceinline__ ushort f2bf(float f) {
  uint u = __float_as_uint(f);
  u += 0x7FFFu + ((u >> 16) & 1u);   // round-to-nearest-even
  return (ushort)(u >> 16);
}
__device__ __forceinline__ float bf2f(ushort h) {
  return __uint_as_float(((uint)h) << 16);
}

// ---------------------------------------------------------------------------
// fp32 -> bf16 elementwise convert (4 elems/thread)
// ---------------------------------------------------------------------------
__global__ __launch_bounds__(256) void cvt_bf16(
    const float* __restrict__ in, ushort* __restrict__ out, int n4)
{
  int i = blockIdx.x * 256 + threadIdx.x;
  if (i >= n4) return;
  float4 v = ((const float4*)in)[i];
  ushort4 o;
  o.x = f2bf(v.x); o.y = f2bf(v.y); o.z = f2bf(v.z); o.w = f2bf(v.w);
  ((ushort4*)out)[i] = o;
}

// ---------------------------------------------------------------------------
// fp32 NT GEMM, MODE 0 only: sc_raw[r] += ||x_r @ wj^T||^2 partial (atomic).
// Precision-critical path (score exponent amplifies errors ~10x) — stays fp32.
// ---------------------------------------------------------------------------
template<int MODE>
__global__ __launch_bounds__(256) void gemm_nt(
    const float* __restrict__ A, const float* __restrict__ W,
    float* __restrict__ C, float* __restrict__ aux)
{
  const int K = 1024;
  __shared__ float As[16][68];
  __shared__ float Bs[16][68];
  const int m0 = blockIdx.y * 64;
  const int n0 = blockIdx.x * 64;
  const int tid = threadIdx.x;
  const int lr = tid >> 2;
  const int lk = (tid & 3) << 2;
  const float* Ap = A + (size_t)(m0 + lr) * K + lk;
  const float* Wp = W + (size_t)(n0 + lr) * K + lk;
  const int tt = (tid >> 4) << 2;
  const int nn = (tid & 15) << 2;

  float acc[4][4] = {};
  for (int k0 = 0; k0 < K; k0 += 16) {
    const float4 av = *(const float4*)(Ap + k0);
    const float4 wv = *(const float4*)(Wp + k0);
    As[lk+0][lr]=av.x; As[lk+1][lr]=av.y; As[lk+2][lr]=av.z; As[lk+3][lr]=av.w;
    Bs[lk+0][lr]=wv.x; Bs[lk+1][lr]=wv.y; Bs[lk+2][lr]=wv.z; Bs[lk+3][lr]=wv.w;
    __syncthreads();
#pragma unroll
    for (int k = 0; k < 16; ++k) {
      const float4 a4 = *(const float4*)&As[k][tt];
      const float4 b4 = *(const float4*)&Bs[k][nn];
      const float a[4] = {a4.x, a4.y, a4.z, a4.w};
      const float bv[4] = {b4.x, b4.y, b4.z, b4.w};
#pragma unroll
      for (int i = 0; i < 4; ++i)
#pragma unroll
        for (int j = 0; j < 4; ++j)
          acc[i][j] = fmaf(a[i], bv[j], acc[i][j]);
    }
    __syncthreads();
  }

  __shared__ float red[64][17];
#pragma unroll
  for (int i = 0; i < 4; ++i) {
    const float s = acc[i][0]*acc[i][0] + acc[i][1]*acc[i][1]
                  + acc[i][2]*acc[i][2] + acc[i][3]*acc[i][3];
    red[tt + i][tid & 15] = s;
  }
  __syncthreads();
  if (tid < 64) {
    float s = 0.f;
#pragma unroll
    for (int j = 0; j < 16; ++j) s += red[tid][j];
    atomicAdd(&aux[m0 + tid], s);
  }
  (void)C;
}

// ---------------------------------------------------------------------------
// sc = sc_raw/32; pmax = inclusive prefix max per batch (sc >= 0 always).
// ---------------------------------------------------------------------------
__global__ __launch_bounds__(1024) void scan_max(
    const float* __restrict__ sc_raw, float* __restrict__ sc,
    float* __restrict__ pmax)
{
  const int b = blockIdx.x;
  __shared__ float b0[T_SEQ];
  __shared__ float b1[T_SEQ];
  const int tid = threadIdx.x;
  for (int i = tid; i < T_SEQ; i += 1024) {
    const float v = sc_raw[b*T_SEQ + i] * 0.03125f;
    b0[i] = v;
    sc[b*T_SEQ + i] = v;
  }
  __syncthreads();
  float* src = b0; float* dst = b1;
  for (int off = 1; off < T_SEQ; off <<= 1) {
    for (int i = tid; i < T_SEQ; i += 1024)
      dst[i] = (i >= off) ? fmaxf(src[i], src[i - off]) : src[i];
    __syncthreads();
    float* tmp = src; src = dst; dst = tmp;
  }
  for (int i = tid; i < T_SEQ; i += 1024) pmax[b*T_SEQ + i] = src[i];
}

// ---------------------------------------------------------------------------
// bf16 MFMA NT GEMM: C[m][n] = sum_k A[m][k]*B[n][k].  128x128 tile, BK=32,
// 256 thr = 4 waves, each wave 64x64 via 4x4 tiles of 16x16x32 MFMA.
// OUT_BF16: store bf16 (valT) else fp32 (final output).
// ---------------------------------------------------------------------------
template<bool OUT_BF16>
__global__ __launch_bounds__(256) void gemm_bf16(
    const ushort* __restrict__ A, const ushort* __restrict__ B,
    void* __restrict__ Cout, int M, int N, int K)
{
  __shared__ ushort As[128][40];  // pad 40: 80B row stride -> 4-way max on b128
  __shared__ ushort Bs[128][40];
  const int tid = threadIdx.x;
  const int m0 = blockIdx.y * 128, n0 = blockIdx.x * 128;
  const int wave = tid >> 6, lane = tid & 63;
  const int l15 = lane & 15, lq = lane >> 4;
  const int wm = (wave & 1) * 64, wn = (wave >> 1) * 64;
  const int srow = tid >> 2, scol = (tid & 3) * 8;

  f32x4 acc[4][4] = {};
  const ushort* Ap = A + (size_t)(m0 + srow) * K + scol;
  const ushort* Bp = B + (size_t)(n0 + srow) * K + scol;

  for (int k0 = 0; k0 < K; k0 += 32) {
    const uint4 a0 = *(const uint4*)(Ap + k0);
    const uint4 a1 = *(const uint4*)(Ap + (size_t)64 * K + k0);
    const uint4 b0 = *(const uint4*)(Bp + k0);
    const uint4 b1 = *(const uint4*)(Bp + (size_t)64 * K + k0);
    __syncthreads();              // prior iter's frag reads complete
    *(uint4*)&As[srow     ][scol] = a0;
    *(uint4*)&As[srow + 64][scol] = a1;
    *(uint4*)&Bs[srow     ][scol] = b0;
    *(uint4*)&Bs[srow + 64][scol] = b1;
    __syncthreads();
    short8 af[4], bfr[4];
#pragma unroll
    for (int i = 0; i < 4; ++i)
      af[i] = *(const short8*)&As[wm + i*16 + l15][lq*8];
#pragma unroll
    for (int j = 0; j < 4; ++j)
      bfr[j] = *(const short8*)&Bs[wn + j*16 + l15][lq*8];
#pragma unroll
    for (int i = 0; i < 4; ++i)
#pragma unroll
      for (int j = 0; j < 4; ++j)
        acc[i][j] = __builtin_amdgcn_mfma_f32_16x16x32_bf16(af[i], bfr[j], acc[i][j], 0, 0, 0);
  }

  // C/D layout: col = lane&15, row = (lane>>4)*4 + reg  [m89/m91 verified]
#pragma unroll
  for (int i = 0; i < 4; ++i)
#pragma unroll
    for (int j = 0; j < 4; ++j) {
      const int mb = m0 + wm + i*16 + lq*4;
      const int nb = n0 + wn + j*16 + l15;
#pragma unroll
      for (int r = 0; r < 4; ++r) {
        if (OUT_BF16)
          ((ushort*)Cout)[(size_t)(mb + r) * N + nb] = f2bf(acc[i][j][r]);
        else
          ((float*)Cout)[(size_t)(mb + r) * N + nb] = acc[i][j][r];
      }
    }
}

// ---------------------------------------------------------------------------
// Fused causal rank-1 attention, bf16 MFMA P·V, normalized in-kernel.
// Tile: 64 t x 128 e; chunks of 64 s. valT layout [E][R] so B-frags are
// s-contiguous. P in LDS padded to 72 (no 16-way conflicts).
// Each block sees ALL s<=t chunks -> owns full Z row sum -> normalize here.
// ---------------------------------------------------------------------------
__global__ __launch_bounds__(256) void attn_mfma(
    const ushort* __restrict__ valT, const float* __restrict__ sc,
    const float* __restrict__ pmax, ushort* __restrict__ attnN)
{
  __shared__ ushort p[64][72];
  __shared__ ushort vsT[128][72];
  __shared__ float zsh[64][5];
  __shared__ float zinv[64];

  const int b  = blockIdx.z;
  const int ty = (int)gridDim.y - 1 - (int)blockIdx.y;  // heavy blocks first
  const int t0 = ty * 64;
  const int e0 = blockIdx.x * 128;
  const int tid = threadIdx.x;
  const int wave = tid >> 6, lane = tid & 63;
  const int l15 = lane & 15, lq = lane >> 4;
  const int wm = (wave & 1) * 32, wn = (wave >> 1) * 64;
  const int prow = tid >> 2, pcb = (tid & 3) * 16;

  const int   tglob = t0 + prow;
  const float st = sc[b*T_SEQ + tglob];
  const float pm = pmax[b*T_SEQ + tglob];

  f32x4 acc[2][4] = {};
  float zp = 0.f;

  for (int c = 0; c <= ty; ++c) {
    const int s0 = c * 64;
    // global loads first (overlap with prior iter's compute)
    uint4 vstage[4];
#pragma unroll
    for (int q = 0; q < 4; ++q) {
      const int slot = q * 256 + tid;
      const int row = slot >> 3, col = (slot & 7) * 8;
      vstage[q] = *(const uint4*)&valT[(size_t)(e0 + row) * R_ROWS + b*T_SEQ + s0 + col];
    }
    float4 s4[4];
#pragma unroll
    for (int q = 0; q < 4; ++q)
      s4[q] = *(const float4*)&sc[b*T_SEQ + s0 + pcb + 4*q];

    __syncthreads();              // prior iter's p/vsT reads complete
#pragma unroll
    for (int q = 0; q < 4; ++q) {
      const int slot = q * 256 + tid;
      const int row = slot >> 3, col = (slot & 7) * 8;
      *(uint4*)&vsT[row][col] = vstage[q];
    }
    // P generation: fp32 exp -> bf16; Z accumulates the bf16-rounded values
    ushort tmp[16];
#pragma unroll
    for (int k = 0; k < 16; ++k) {
      const int sglob = s0 + pcb + k;
      const float sv = ((const float*)s4)[k];
      float pe = 0.f;
      if (sglob <= tglob) pe = __expf(st * (sv - pm));
      const ushort h = f2bf(pe);
      tmp[k] = h;
      zp += bf2f(h);
    }
    *(uint4*)&p[prow][pcb    ] = *(const uint4*)&tmp[0];
    *(uint4*)&p[prow][pcb + 8] = *(const uint4*)&tmp[8];
    __syncthreads();

#pragma unroll
    for (int ks = 0; ks < 64; ks += 32) {
      short8 af[2], bfr[4];
#pragma unroll
      for (int i = 0; i < 2; ++i)
        af[i] = *(const short8*)&p[wm + i*16 + l15][ks + lq*8];
#pragma unroll
      for (int j = 0; j < 4; ++j)
        bfr[j] = *(const short8*)&vsT[wn + j*16 + l15][ks + lq*8];
#pragma unroll
      for (int i = 0; i < 2; ++i)
#pragma unroll
        for (int j = 0; j < 4; ++j)
          acc[i][j] = __builtin_amdgcn_mfma_f32_16x16x32_bf16(af[i], bfr[j], acc[i][j], 0, 0, 0);
    }
  }

  // Z reduce (4 partials per t-row) and normalize epilogue
  zsh[prow][tid & 3] = zp;
  __syncthreads();
  if (tid < 64) {
    const float z = zsh[tid][0] + zsh[tid][1] + zsh[tid][2] + zsh[tid][3];
    zinv[tid] = 1.0f / z;
  }
  __syncthreads();

#pragma unroll
  for (int i = 0; i < 2; ++i)
#pragma unroll
    for (int j = 0; j < 4; ++j) {
      const int nb = e0 + wn + j*16 + l15;
#pragma unroll
      for (int r = 0; r < 4; ++r) {
        const int ml = wm + i*16 + lq*4 + r;
        const float v = acc[i][j][r] * zinv[ml];
        attnN[(size_t)(b*T_SEQ + t0 + ml) * E_DIM + nb] = f2bf(v);
      }
    }
}

// ---------------------------------------------------------------------------
extern "C" void kernel_launch(void* const* d_in, const int* in_sizes, int n_in,
                              void* d_out, int out_size, void* d_ws, size_t ws_size,
                              hipStream_t stream) {
  (void)in_sizes; (void)n_in; (void)out_size; (void)ws_size;
  const float* x   = (const float*)d_in[0];
  const float* wj  = (const float*)d_in[1];
  const float* wjv = (const float*)d_in[2];
  const float* wo  = (const float*)d_in[3];
  float* out = (float*)d_out;

  ushort* xb    = (ushort*)d_ws;                        // 16 MB
  ushort* wjvb  = xb    + (size_t)R_ROWS * E_DIM;       // 2 MB
  ushort* wob   = wjvb  + (size_t)E_DIM * E_DIM;        // 2 MB
  ushort* valT  = wob   + (size_t)E_DIM * E_DIM;        // 16 MB  [E][R]
  ushort* attnN = valT  + (size_t)E_DIM * R_ROWS;       // 16 MB  [R][E]
  float* sc_raw = (float*)(attnN + (size_t)R_ROWS * E_DIM);
  float* sc     = sc_raw + R_ROWS;
  float* pmax   = sc + R_ROWS;

  hipMemsetAsync(sc_raw, 0, R_ROWS * sizeof(float), stream);

  cvt_bf16<<<R_ROWS*E_DIM/4/256, 256, 0, stream>>>(x,   xb,   R_ROWS*E_DIM/4);
  cvt_bf16<<<E_DIM*E_DIM/4/256, 256, 0, stream>>>(wjv, wjvb, E_DIM*E_DIM/4);
  cvt_bf16<<<E_DIM*E_DIM/4/256, 256, 0, stream>>>(wo,  wob,  E_DIM*E_DIM/4);

  // sc_raw[r] = ||x_r @ wj^T||^2   (fp32, precision-critical)
  gemm_nt<0><<<dim3(16, 128), 256, 0, stream>>>(x, wj, nullptr, sc_raw);
  scan_max<<<4, 1024, 0, stream>>>(sc_raw, sc, pmax);

  // valT[e][r] = sum_k wjv[e][k] * x[r][k]   (bf16 MFMA, M=1024 N=8192)
  gemm_bf16<true><<<dim3(R_ROWS/128, E_DIM/128), 256, 0, stream>>>(
      wjvb, xb, valT, E_DIM, R_ROWS, E_DIM);

  // normalized attention output, bf16
  attn_mfma<<<dim3(E_DIM/128, T_SEQ/64, 4), 256, 0, stream>>>(valT, sc, pmax, attnN);

  // out = attnN @ wo^T   (bf16 MFMA, fp32 out, M=8192 N=1024)
  gemm_bf16<false><<<dim3(E_DIM/128, R_ROWS/128), 256, 0, stream>>>(
      attnN, wob, out, R_ROWS, E_DIM, E_DIM);
}

// Round 3
// 380.931 us; speedup vs baseline: 2.8824x; 1.4584x over previous
//
#include <hip/hip_runtime.h>
#include <math.h>

// B=4, T=2048, E=1024, H*D=1024; R = B*T = 8192.
#define R_ROWS 8192
#define T_SEQ  2048
#define E_DIM  1024

typedef __attribute__((ext_vector_type(8))) short short8;
typedef __attribute__((ext_vector_type(4))) float f32x4;

__device__ __forceinline__ ushort f2bf(float f) {
  uint u = __float_as_uint(f);
  u += 0x7FFFu + ((u >> 16) & 1u);   // round-to-nearest-even
  return (ushort)(u >> 16);
}
__device__ __forceinline__ float bf2f(ushort h) {
  return __uint_as_float(((uint)h) << 16);
}

// ---------------------------------------------------------------------------
// fp32 -> bf16 elementwise convert (4 elems/thread)
// ---------------------------------------------------------------------------
__global__ __launch_bounds__(256) void cvt_bf16(
    const float* __restrict__ in, ushort* __restrict__ out, int n4)
{
  int i = blockIdx.x * 256 + threadIdx.x;
  if (i >= n4) return;
  float4 v = ((const float4*)in)[i];
  ushort4 o;
  o.x = f2bf(v.x); o.y = f2bf(v.y); o.z = f2bf(v.z); o.w = f2bf(v.w);
  ((ushort4*)out)[i] = o;
}

// ---------------------------------------------------------------------------
// fp32 -> (bf16 hi, bf16 lo) split: v = hi + lo + O(2^-18 * v).
// Subtraction v - hi is exact in fp32 (Sterbenz), lo is the rounded residual.
// ---------------------------------------------------------------------------
__global__ __launch_bounds__(256) void cvt_split(
    const float* __restrict__ in, ushort* __restrict__ hi,
    ushort* __restrict__ lo, int n4)
{
  int i = blockIdx.x * 256 + threadIdx.x;
  if (i >= n4) return;
  float4 v = ((const float4*)in)[i];
  ushort4 h, l;
  h.x = f2bf(v.x); l.x = f2bf(v.x - bf2f(h.x));
  h.y = f2bf(v.y); l.y = f2bf(v.y - bf2f(h.y));
  h.z = f2bf(v.z); l.z = f2bf(v.z - bf2f(h.z));
  h.w = f2bf(v.w); l.w = f2bf(v.w - bf2f(h.w));
  ((ushort4*)hi)[i] = h;
  ((ushort4*)lo)[i] = l;
}

// ---------------------------------------------------------------------------
// Split-bf16 "fp32-emulated" MFMA GEMM for the precision-critical sc path:
//   echo[m][n] = sum_k x[m][k]*wj[n][k]  via  xh*wh + xh*wl + xl*wh
//   sc_raw[m] += sum_n echo[m][n]^2      (echo never materialized)
// 128x128 tile, BK=32, 4 waves, 3 MFMAs per (i,j) k-step.
// Dropped lo*lo term contributes ~2e-6 to echo -> delta(sc) ~1e-5: fp32-grade.
// ---------------------------------------------------------------------------
__global__ __launch_bounds__(256) void gemm_sq_split(
    const ushort* __restrict__ xh, const ushort* __restrict__ xl,
    const ushort* __restrict__ wh, const ushort* __restrict__ wl,
    float* __restrict__ sc_raw)
{
  const int K = 1024;
  __shared__ ushort Ah[128][40];
  __shared__ ushort Al[128][40];
  __shared__ ushort Bh[128][40];
  __shared__ ushort Bl[128][40];
  const int tid = threadIdx.x;
  const int m0 = blockIdx.y * 128, n0 = blockIdx.x * 128;
  const int wave = tid >> 6, lane = tid & 63;
  const int l15 = lane & 15, lq = lane >> 4;
  const int wm = (wave & 1) * 64, wn = (wave >> 1) * 64;
  const int srow = tid >> 2, scol = (tid & 3) * 8;

  f32x4 acc[4][4] = {};
  const ushort* xhp = xh + (size_t)(m0 + srow) * K + scol;
  const ushort* xlp = xl + (size_t)(m0 + srow) * K + scol;
  const ushort* whp = wh + (size_t)(n0 + srow) * K + scol;
  const ushort* wlp = wl + (size_t)(n0 + srow) * K + scol;

  for (int k0 = 0; k0 < K; k0 += 32) {
    const uint4 ah0 = *(const uint4*)(xhp + k0);
    const uint4 ah1 = *(const uint4*)(xhp + (size_t)64*K + k0);
    const uint4 al0 = *(const uint4*)(xlp + k0);
    const uint4 al1 = *(const uint4*)(xlp + (size_t)64*K + k0);
    const uint4 bh0 = *(const uint4*)(whp + k0);
    const uint4 bh1 = *(const uint4*)(whp + (size_t)64*K + k0);
    const uint4 bl0 = *(const uint4*)(wlp + k0);
    const uint4 bl1 = *(const uint4*)(wlp + (size_t)64*K + k0);
    __syncthreads();
    *(uint4*)&Ah[srow][scol] = ah0;  *(uint4*)&Ah[srow+64][scol] = ah1;
    *(uint4*)&Al[srow][scol] = al0;  *(uint4*)&Al[srow+64][scol] = al1;
    *(uint4*)&Bh[srow][scol] = bh0;  *(uint4*)&Bh[srow+64][scol] = bh1;
    *(uint4*)&Bl[srow][scol] = bl0;  *(uint4*)&Bl[srow+64][scol] = bl1;
    __syncthreads();
    short8 bhf[4], blf[4];
#pragma unroll
    for (int j = 0; j < 4; ++j) {
      bhf[j] = *(const short8*)&Bh[wn + j*16 + l15][lq*8];
      blf[j] = *(const short8*)&Bl[wn + j*16 + l15][lq*8];
    }
#pragma unroll
    for (int i = 0; i < 4; ++i) {
      const short8 ahf = *(const short8*)&Ah[wm + i*16 + l15][lq*8];
      const short8 alf = *(const short8*)&Al[wm + i*16 + l15][lq*8];
#pragma unroll
      for (int j = 0; j < 4; ++j) {
        acc[i][j] = __builtin_amdgcn_mfma_f32_16x16x32_bf16(ahf, bhf[j], acc[i][j], 0, 0, 0);
        acc[i][j] = __builtin_amdgcn_mfma_f32_16x16x32_bf16(ahf, blf[j], acc[i][j], 0, 0, 0);
        acc[i][j] = __builtin_amdgcn_mfma_f32_16x16x32_bf16(alf, bhf[j], acc[i][j], 0, 0, 0);
      }
    }
  }

  // Epilogue: per-row sum of squares over this block's 128 cols, then atomic.
  // Reuse staging LDS (Ah/Al span 20 KB > 128*33*4 = 16.9 KB).
  __syncthreads();
  float* red = (float*)&Ah[0][0];
#pragma unroll
  for (int i = 0; i < 4; ++i)
#pragma unroll
    for (int r = 0; r < 4; ++r) {
      const int row = wm + i*16 + lq*4 + r;   // C/D: row = lq*4+reg [m89/m91]
      float s = 0.f;
#pragma unroll
      for (int j = 0; j < 4; ++j) s += acc[i][j][r] * acc[i][j][r];
      red[row*33 + (wave>>1)*16 + l15] = s;
    }
  __syncthreads();
  if (tid < 128) {
    float s = 0.f;
#pragma unroll
    for (int c = 0; c < 32; ++c) s += red[tid*33 + c];
    atomicAdd(&sc_raw[m0 + tid], s);
  }
}

// ---------------------------------------------------------------------------
// sc = sc_raw/32; pmax = inclusive prefix max per batch (sc >= 0 always).
// ---------------------------------------------------------------------------
__global__ __launch_bounds__(1024) void scan_max(
    const float* __restrict__ sc_raw, float* __restrict__ sc,
    float* __restrict__ pmax)
{
  const int b = blockIdx.x;
  __shared__ float b0[T_SEQ];
  __shared__ float b1[T_SEQ];
  const int tid = threadIdx.x;
  for (int i = tid; i < T_SEQ; i += 1024) {
    const float v = sc_raw[b*T_SEQ + i] * 0.03125f;
    b0[i] = v;
    sc[b*T_SEQ + i] = v;
  }
  __syncthreads();
  float* src = b0; float* dst = b1;
  for (int off = 1; off < T_SEQ; off <<= 1) {
    for (int i = tid; i < T_SEQ; i += 1024)
      dst[i] = (i >= off) ? fmaxf(src[i], src[i - off]) : src[i];
    __syncthreads();
    float* tmp = src; src = dst; dst = tmp;
  }
  for (int i = tid; i < T_SEQ; i += 1024) pmax[b*T_SEQ + i] = src[i];
}

// ---------------------------------------------------------------------------
// bf16 MFMA NT GEMM: C[m][n] = sum_k A[m][k]*B[n][k].  128x128 tile, BK=32,
// 256 thr = 4 waves, each wave 64x64 via 4x4 tiles of 16x16x32 MFMA.
// OUT_BF16: store bf16 (valT) else fp32 (final output).
// ---------------------------------------------------------------------------
template<bool OUT_BF16>
__global__ __launch_bounds__(256) void gemm_bf16(
    const ushort* __restrict__ A, const ushort* __restrict__ B,
    void* __restrict__ Cout, int M, int N, int K)
{
  __shared__ ushort As[128][40];
  __shared__ ushort Bs[128][40];
  const int tid = threadIdx.x;
  const int m0 = blockIdx.y * 128, n0 = blockIdx.x * 128;
  const int wave = tid >> 6, lane = tid & 63;
  const int l15 = lane & 15, lq = lane >> 4;
  const int wm = (wave & 1) * 64, wn = (wave >> 1) * 64;
  const int srow = tid >> 2, scol = (tid & 3) * 8;

  f32x4 acc[4][4] = {};
  const ushort* Ap = A + (size_t)(m0 + srow) * K + scol;
  const ushort* Bp = B + (size_t)(n0 + srow) * K + scol;

  for (int k0 = 0; k0 < K; k0 += 32) {
    const uint4 a0 = *(const uint4*)(Ap + k0);
    const uint4 a1 = *(const uint4*)(Ap + (size_t)64 * K + k0);
    const uint4 b0 = *(const uint4*)(Bp + k0);
    const uint4 b1 = *(const uint4*)(Bp + (size_t)64 * K + k0);
    __syncthreads();
    *(uint4*)&As[srow     ][scol] = a0;
    *(uint4*)&As[srow + 64][scol] = a1;
    *(uint4*)&Bs[srow     ][scol] = b0;
    *(uint4*)&Bs[srow + 64][scol] = b1;
    __syncthreads();
    short8 af[4], bfr[4];
#pragma unroll
    for (int i = 0; i < 4; ++i)
      af[i] = *(const short8*)&As[wm + i*16 + l15][lq*8];
#pragma unroll
    for (int j = 0; j < 4; ++j)
      bfr[j] = *(const short8*)&Bs[wn + j*16 + l15][lq*8];
#pragma unroll
    for (int i = 0; i < 4; ++i)
#pragma unroll
      for (int j = 0; j < 4; ++j)
        acc[i][j] = __builtin_amdgcn_mfma_f32_16x16x32_bf16(af[i], bfr[j], acc[i][j], 0, 0, 0);
  }

#pragma unroll
  for (int i = 0; i < 4; ++i)
#pragma unroll
    for (int j = 0; j < 4; ++j) {
      const int mb = m0 + wm + i*16 + lq*4;
      const int nb = n0 + wn + j*16 + l15;
#pragma unroll
      for (int r = 0; r < 4; ++r) {
        if (OUT_BF16)
          ((ushort*)Cout)[(size_t)(mb + r) * N + nb] = f2bf(acc[i][j][r]);
        else
          ((float*)Cout)[(size_t)(mb + r) * N + nb] = acc[i][j][r];
      }
    }
}

// ---------------------------------------------------------------------------
// Fused causal rank-1 attention, bf16 MFMA P·V, normalized in-kernel.
// ---------------------------------------------------------------------------
__global__ __launch_bounds__(256) void attn_mfma(
    const ushort* __restrict__ valT, const float* __restrict__ sc,
    const float* __restrict__ pmax, ushort* __restrict__ attnN)
{
  __shared__ ushort p[64][72];
  __shared__ ushort vsT[128][72];
  __shared__ float zsh[64][5];
  __shared__ float zinv[64];

  const int b  = blockIdx.z;
  const int ty = (int)gridDim.y - 1 - (int)blockIdx.y;  // heavy blocks first
  const int t0 = ty * 64;
  const int e0 = blockIdx.x * 128;
  const int tid = threadIdx.x;
  const int wave = tid >> 6, lane = tid & 63;
  const int l15 = lane & 15, lq = lane >> 4;
  const int wm = (wave & 1) * 32, wn = (wave >> 1) * 64;
  const int prow = tid >> 2, pcb = (tid & 3) * 16;

  const int   tglob = t0 + prow;
  const float st = sc[b*T_SEQ + tglob];
  const float pm = pmax[b*T_SEQ + tglob];

  f32x4 acc[2][4] = {};
  float zp = 0.f;

  for (int c = 0; c <= ty; ++c) {
    const int s0 = c * 64;
    uint4 vstage[4];
#pragma unroll
    for (int q = 0; q < 4; ++q) {
      const int slot = q * 256 + tid;
      const int row = slot >> 3, col = (slot & 7) * 8;
      vstage[q] = *(const uint4*)&valT[(size_t)(e0 + row) * R_ROWS + b*T_SEQ + s0 + col];
    }
    float4 s4[4];
#pragma unroll
    for (int q = 0; q < 4; ++q)
      s4[q] = *(const float4*)&sc[b*T_SEQ + s0 + pcb + 4*q];

    __syncthreads();
#pragma unroll
    for (int q = 0; q < 4; ++q) {
      const int slot = q * 256 + tid;
      const int row = slot >> 3, col = (slot & 7) * 8;
      *(uint4*)&vsT[row][col] = vstage[q];
    }
    ushort tmp[16];
#pragma unroll
    for (int k = 0; k < 16; ++k) {
      const int sglob = s0 + pcb + k;
      const float sv = ((const float*)s4)[k];
      float pe = 0.f;
      if (sglob <= tglob) pe = __expf(st * (sv - pm));
      const ushort h = f2bf(pe);
      tmp[k] = h;
      zp += bf2f(h);
    }
    *(uint4*)&p[prow][pcb    ] = *(const uint4*)&tmp[0];
    *(uint4*)&p[prow][pcb + 8] = *(const uint4*)&tmp[8];
    __syncthreads();

#pragma unroll
    for (int ks = 0; ks < 64; ks += 32) {
      short8 af[2], bfr[4];
#pragma unroll
      for (int i = 0; i < 2; ++i)
        af[i] = *(const short8*)&p[wm + i*16 + l15][ks + lq*8];
#pragma unroll
      for (int j = 0; j < 4; ++j)
        bfr[j] = *(const short8*)&vsT[wn + j*16 + l15][ks + lq*8];
#pragma unroll
      for (int i = 0; i < 2; ++i)
#pragma unroll
        for (int j = 0; j < 4; ++j)
          acc[i][j] = __builtin_amdgcn_mfma_f32_16x16x32_bf16(af[i], bfr[j], acc[i][j], 0, 0, 0);
    }
  }

  zsh[prow][tid & 3] = zp;
  __syncthreads();
  if (tid < 64) {
    const float z = zsh[tid][0] + zsh[tid][1] + zsh[tid][2] + zsh[tid][3];
    zinv[tid] = 1.0f / z;
  }
  __syncthreads();

#pragma unroll
  for (int i = 0; i < 2; ++i)
#pragma unroll
    for (int j = 0; j < 4; ++j) {
      const int nb = e0 + wn + j*16 + l15;
#pragma unroll
      for (int r = 0; r < 4; ++r) {
        const int ml = wm + i*16 + lq*4 + r;
        const float v = acc[i][j][r] * zinv[ml];
        attnN[(size_t)(b*T_SEQ + t0 + ml) * E_DIM + nb] = f2bf(v);
      }
    }
}

// ---------------------------------------------------------------------------
extern "C" void kernel_launch(void* const* d_in, const int* in_sizes, int n_in,
                              void* d_out, int out_size, void* d_ws, size_t ws_size,
                              hipStream_t stream) {
  (void)in_sizes; (void)n_in; (void)out_size; (void)ws_size;
  const float* x   = (const float*)d_in[0];
  const float* wj  = (const float*)d_in[1];
  const float* wjv = (const float*)d_in[2];
  const float* wo  = (const float*)d_in[3];
  float* out = (float*)d_out;

  ushort* xh    = (ushort*)d_ws;                        // 16 MB (bf16 x, also val GEMM input)
  ushort* xl    = xh    + (size_t)R_ROWS * E_DIM;       // 16 MB (aliased by attnN later)
  ushort* wjh   = xl    + (size_t)R_ROWS * E_DIM;       // 2 MB
  ushort* wjl   = wjh   + (size_t)E_DIM * E_DIM;        // 2 MB
  ushort* wjvb  = wjl   + (size_t)E_DIM * E_DIM;        // 2 MB
  ushort* wob   = wjvb  + (size_t)E_DIM * E_DIM;        // 2 MB
  ushort* valT  = wob   + (size_t)E_DIM * E_DIM;        // 16 MB  [E][R]
  float* sc_raw = (float*)(valT + (size_t)E_DIM * R_ROWS);
  float* sc     = sc_raw + R_ROWS;
  float* pmax   = sc + R_ROWS;
  ushort* attnN = xl;   // xl is dead after gemm_sq_split (stream-serial)

  hipMemsetAsync(sc_raw, 0, R_ROWS * sizeof(float), stream);

  cvt_split<<<R_ROWS*E_DIM/4/256, 256, 0, stream>>>(x,  xh,  xl,  R_ROWS*E_DIM/4);
  cvt_split<<<E_DIM*E_DIM/4/256, 256, 0, stream>>>(wj, wjh, wjl, E_DIM*E_DIM/4);
  cvt_bf16<<<E_DIM*E_DIM/4/256, 256, 0, stream>>>(wjv, wjvb, E_DIM*E_DIM/4);
  cvt_bf16<<<E_DIM*E_DIM/4/256, 256, 0, stream>>>(wo,  wob,  E_DIM*E_DIM/4);

  // sc_raw[r] = ||x_r @ wj^T||^2  via split-bf16 MFMA (fp32-grade accuracy)
  gemm_sq_split<<<dim3(E_DIM/128, R_ROWS/128), 256, 0, stream>>>(
      xh, xl, wjh, wjl, sc_raw);
  scan_max<<<4, 1024, 0, stream>>>(sc_raw, sc, pmax);

  // valT[e][r] = sum_k wjv[e][k] * x[r][k]   (bf16 MFMA, M=1024 N=8192)
  gemm_bf16<true><<<dim3(R_ROWS/128, E_DIM/128), 256, 0, stream>>>(
      wjvb, xh, valT, E_DIM, R_ROWS, E_DIM);

  // normalized attention output, bf16
  attn_mfma<<<dim3(E_DIM/128, T_SEQ/64, 4), 256, 0, stream>>>(valT, sc, pmax, attnN);

  // out = attnN @ wo^T   (bf16 MFMA, fp32 out, M=8192 N=1024)
  gemm_bf16<false><<<dim3(E_DIM/128, R_ROWS/128), 256, 0, stream>>>(
      attnN, wob, out, R_ROWS, E_DIM, E_DIM);
}

// Round 4
// 277.828 us; speedup vs baseline: 3.9520x; 1.3711x over previous
//
#include <hip/hip_runtime.h>
#include <math.h>

// B=4, T=2048, E=1024, H*D=1024; R = B*T = 8192.
#define R_ROWS 8192
#define T_SEQ  2048
#define E_DIM  1024

typedef __attribute__((ext_vector_type(8))) short short8;
typedef __attribute__((ext_vector_type(4))) float f32x4;

__device__ __forceinline__ ushort f2bf(float f) {
  uint u = __float_as_uint(f);
  u += 0x7FFFu + ((u >> 16) & 1u);   // round-to-nearest-even
  return (ushort)(u >> 16);
}
__device__ __forceinline__ float bf2f(ushort h) {
  return __uint_as_float(((uint)h) << 16);
}

// ---------------------------------------------------------------------------
// fp32 -> bf16 elementwise convert (4 elems/thread)
// ---------------------------------------------------------------------------
__global__ __launch_bounds__(256) void cvt_bf16(
    const float* __restrict__ in, ushort* __restrict__ out, int n4)
{
  int i = blockIdx.x * 256 + threadIdx.x;
  if (i >= n4) return;
  float4 v = ((const float4*)in)[i];
  ushort4 o;
  o.x = f2bf(v.x); o.y = f2bf(v.y); o.z = f2bf(v.z); o.w = f2bf(v.w);
  ((ushort4*)out)[i] = o;
}

// ---------------------------------------------------------------------------
// fp32 -> (bf16 hi, bf16 lo) split: v = hi + lo + O(2^-18 * v).
// ---------------------------------------------------------------------------
__global__ __launch_bounds__(256) void cvt_split(
    const float* __restrict__ in, ushort* __restrict__ hi,
    ushort* __restrict__ lo, int n4)
{
  int i = blockIdx.x * 256 + threadIdx.x;
  if (i >= n4) return;
  float4 v = ((const float4*)in)[i];
  ushort4 h, l;
  h.x = f2bf(v.x); l.x = f2bf(v.x - bf2f(h.x));
  h.y = f2bf(v.y); l.y = f2bf(v.y - bf2f(h.y));
  h.z = f2bf(v.z); l.z = f2bf(v.z - bf2f(h.z));
  h.w = f2bf(v.w); l.w = f2bf(v.w - bf2f(h.w));
  ((ushort4*)hi)[i] = h;
  ((ushort4*)lo)[i] = l;
}

// ---------------------------------------------------------------------------
// Split-bf16 "fp32-emulated" MFMA GEMM for the precision-critical sc path:
//   sc_raw[m] += sum_n (sum_k x[m][k]*wj[n][k])^2  via xh*wh + xh*wl + xl*wh
// ---------------------------------------------------------------------------
__global__ __launch_bounds__(256) void gemm_sq_split(
    const ushort* __restrict__ xh, const ushort* __restrict__ xl,
    const ushort* __restrict__ wh, const ushort* __restrict__ wl,
    float* __restrict__ sc_raw)
{
  const int K = 1024;
  __shared__ ushort Ah[128][40];
  __shared__ ushort Al[128][40];
  __shared__ ushort Bh[128][40];
  __shared__ ushort Bl[128][40];
  const int tid = threadIdx.x;
  const int m0 = blockIdx.y * 128, n0 = blockIdx.x * 128;
  const int wave = tid >> 6, lane = tid & 63;
  const int l15 = lane & 15, lq = lane >> 4;
  const int wm = (wave & 1) * 64, wn = (wave >> 1) * 64;
  const int srow = tid >> 2, scol = (tid & 3) * 8;

  f32x4 acc[4][4] = {};
  const ushort* xhp = xh + (size_t)(m0 + srow) * K + scol;
  const ushort* xlp = xl + (size_t)(m0 + srow) * K + scol;
  const ushort* whp = wh + (size_t)(n0 + srow) * K + scol;
  const ushort* wlp = wl + (size_t)(n0 + srow) * K + scol;

  for (int k0 = 0; k0 < K; k0 += 32) {
    const uint4 ah0 = *(const uint4*)(xhp + k0);
    const uint4 ah1 = *(const uint4*)(xhp + (size_t)64*K + k0);
    const uint4 al0 = *(const uint4*)(xlp + k0);
    const uint4 al1 = *(const uint4*)(xlp + (size_t)64*K + k0);
    const uint4 bh0 = *(const uint4*)(whp + k0);
    const uint4 bh1 = *(const uint4*)(whp + (size_t)64*K + k0);
    const uint4 bl0 = *(const uint4*)(wlp + k0);
    const uint4 bl1 = *(const uint4*)(wlp + (size_t)64*K + k0);
    __syncthreads();
    *(uint4*)&Ah[srow][scol] = ah0;  *(uint4*)&Ah[srow+64][scol] = ah1;
    *(uint4*)&Al[srow][scol] = al0;  *(uint4*)&Al[srow+64][scol] = al1;
    *(uint4*)&Bh[srow][scol] = bh0;  *(uint4*)&Bh[srow+64][scol] = bh1;
    *(uint4*)&Bl[srow][scol] = bl0;  *(uint4*)&Bl[srow+64][scol] = bl1;
    __syncthreads();
    short8 bhf[4], blf[4];
#pragma unroll
    for (int j = 0; j < 4; ++j) {
      bhf[j] = *(const short8*)&Bh[wn + j*16 + l15][lq*8];
      blf[j] = *(const short8*)&Bl[wn + j*16 + l15][lq*8];
    }
#pragma unroll
    for (int i = 0; i < 4; ++i) {
      const short8 ahf = *(const short8*)&Ah[wm + i*16 + l15][lq*8];
      const short8 alf = *(const short8*)&Al[wm + i*16 + l15][lq*8];
#pragma unroll
      for (int j = 0; j < 4; ++j) {
        acc[i][j] = __builtin_amdgcn_mfma_f32_16x16x32_bf16(ahf, bhf[j], acc[i][j], 0, 0, 0);
        acc[i][j] = __builtin_amdgcn_mfma_f32_16x16x32_bf16(ahf, blf[j], acc[i][j], 0, 0, 0);
        acc[i][j] = __builtin_amdgcn_mfma_f32_16x16x32_bf16(alf, bhf[j], acc[i][j], 0, 0, 0);
      }
    }
  }

  __syncthreads();
  float* red = (float*)&Ah[0][0];
#pragma unroll
  for (int i = 0; i < 4; ++i)
#pragma unroll
    for (int r = 0; r < 4; ++r) {
      const int row = wm + i*16 + lq*4 + r;
      float s = 0.f;
#pragma unroll
      for (int j = 0; j < 4; ++j) s += acc[i][j][r] * acc[i][j][r];
      red[row*33 + (wave>>1)*16 + l15] = s;
    }
  __syncthreads();
  if (tid < 128) {
    float s = 0.f;
#pragma unroll
    for (int c = 0; c < 32; ++c) s += red[tid*33 + c];
    atomicAdd(&sc_raw[m0 + tid], s);
  }
}

// ---------------------------------------------------------------------------
// sc = sc_raw/32; pmax = inclusive prefix max per batch (sc >= 0 always).
// ---------------------------------------------------------------------------
__global__ __launch_bounds__(1024) void scan_max(
    const float* __restrict__ sc_raw, float* __restrict__ sc,
    float* __restrict__ pmax)
{
  const int b = blockIdx.x;
  __shared__ float b0[T_SEQ];
  __shared__ float b1[T_SEQ];
  const int tid = threadIdx.x;
  for (int i = tid; i < T_SEQ; i += 1024) {
    const float v = sc_raw[b*T_SEQ + i] * 0.03125f;
    b0[i] = v;
    sc[b*T_SEQ + i] = v;
  }
  __syncthreads();
  float* src = b0; float* dst = b1;
  for (int off = 1; off < T_SEQ; off <<= 1) {
    for (int i = tid; i < T_SEQ; i += 1024)
      dst[i] = (i >= off) ? fmaxf(src[i], src[i - off]) : src[i];
    __syncthreads();
    float* tmp = src; src = dst; dst = tmp;
  }
  for (int i = tid; i < T_SEQ; i += 1024) pmax[b*T_SEQ + i] = src[i];
}

// ---------------------------------------------------------------------------
// bf16 MFMA NT GEMM (unchanged from round 3)
// ---------------------------------------------------------------------------
template<bool OUT_BF16>
__global__ __launch_bounds__(256) void gemm_bf16(
    const ushort* __restrict__ A, const ushort* __restrict__ B,
    void* __restrict__ Cout, int M, int N, int K)
{
  __shared__ ushort As[128][40];
  __shared__ ushort Bs[128][40];
  const int tid = threadIdx.x;
  const int m0 = blockIdx.y * 128, n0 = blockIdx.x * 128;
  const int wave = tid >> 6, lane = tid & 63;
  const int l15 = lane & 15, lq = lane >> 4;
  const int wm = (wave & 1) * 64, wn = (wave >> 1) * 64;
  const int srow = tid >> 2, scol = (tid & 3) * 8;

  f32x4 acc[4][4] = {};
  const ushort* Ap = A + (size_t)(m0 + srow) * K + scol;
  const ushort* Bp = B + (size_t)(n0 + srow) * K + scol;

  for (int k0 = 0; k0 < K; k0 += 32) {
    const uint4 a0 = *(const uint4*)(Ap + k0);
    const uint4 a1 = *(const uint4*)(Ap + (size_t)64 * K + k0);
    const uint4 b0 = *(const uint4*)(Bp + k0);
    const uint4 b1 = *(const uint4*)(Bp + (size_t)64 * K + k0);
    __syncthreads();
    *(uint4*)&As[srow     ][scol] = a0;
    *(uint4*)&As[srow + 64][scol] = a1;
    *(uint4*)&Bs[srow     ][scol] = b0;
    *(uint4*)&Bs[srow + 64][scol] = b1;
    __syncthreads();
    short8 af[4], bfr[4];
#pragma unroll
    for (int i = 0; i < 4; ++i)
      af[i] = *(const short8*)&As[wm + i*16 + l15][lq*8];
#pragma unroll
    for (int j = 0; j < 4; ++j)
      bfr[j] = *(const short8*)&Bs[wn + j*16 + l15][lq*8];
#pragma unroll
    for (int i = 0; i < 4; ++i)
#pragma unroll
      for (int j = 0; j < 4; ++j)
        acc[i][j] = __builtin_amdgcn_mfma_f32_16x16x32_bf16(af[i], bfr[j], acc[i][j], 0, 0, 0);
  }

#pragma unroll
  for (int i = 0; i < 4; ++i)
#pragma unroll
    for (int j = 0; j < 4; ++j) {
      const int mb = m0 + wm + i*16 + lq*4;
      const int nb = n0 + wn + j*16 + l15;
#pragma unroll
      for (int r = 0; r < 4; ++r) {
        if (OUT_BF16)
          ((ushort*)Cout)[(size_t)(mb + r) * N + nb] = f2bf(acc[i][j][r]);
        else
          ((float*)Cout)[(size_t)(mb + r) * N + nb] = acc[i][j][r];
      }
    }
}

// ---------------------------------------------------------------------------
// Fused causal rank-1 attention, restructured K-loop:
//  - 512 thr / 8 waves, 128t x 128e tile, 64-s chunks.
//  - paired t-tiles (ty, 15-ty): every block = exactly 34 chunks. Grid 256
//    blocks = 1/CU: zero tail, zero imbalance.
//  - P double-buffered in LDS, ONE barrier per chunk: iter c MFMAs p[c&1]
//    while generating P(c+1) into p[1-(c&1)] and prefetching V-frags (regs).
//  - V (B-operand) fragments loaded straight from L2-resident valT [E][R]
//    (no vsT staging / no second barrier). sc row preloaded to LDS once ->
//    P-gen has no global dependency.
// ---------------------------------------------------------------------------
__global__ __launch_bounds__(512) void attn_mfma(
    const ushort* __restrict__ valT, const float* __restrict__ sc,
    const float* __restrict__ pmax, ushort* __restrict__ attnN)
{
  __shared__ float scs_all[T_SEQ];     // 8 KB: whole sc row for this batch
  __shared__ ushort p[2][128][72];     // 36.9 KB double-buffered P (bf16)
  __shared__ float zsh[128][4];
  __shared__ float zinv[128];

  const int b  = blockIdx.z;
  const int e0 = blockIdx.x * 128;
  const int tid = threadIdx.x;
  const int wave = tid >> 6, lane = tid & 63;
  const int l15 = lane & 15, lq = lane >> 4;
  const int wm = (wave & 1) * 64;        // t-offset of wave (2 t-waves)
  const int wn = (wave >> 1) * 32;       // e-offset of wave (4 e-waves)
  const int bT = b * T_SEQ;

  // preload sc[b][:] into LDS (512 thr x 4 floats)
  *(float4*)&scs_all[tid * 4] = *(const float4*)&sc[bT + tid * 4];
  __syncthreads();

  // P-gen mapping: row prow (0..127), s-cols pc..pc+15 of the chunk
  const int prow = tid >> 2;
  const int pc = (tid & 3) * 16;

#pragma unroll 1
  for (int ph = 0; ph < 2; ++ph) {
    const int ty = ph == 0 ? (15 - (int)blockIdx.y) : (int)blockIdx.y;
    const int t0 = ty * 128;
    const int nchunk = 2 * ty + 2;

    const int tglob = t0 + prow;
    const float st = sc[bT + tglob];
    const float pm = pmax[bT + tglob];

    f32x4 acc[4][2] = {};
    float zp = 0.f;

    auto pgen = [&](int c, int buf) -> float {
      const int s0 = c * 64;
      float sv[16];
#pragma unroll
      for (int q = 0; q < 4; ++q)
        *(float4*)&sv[q*4] = *(const float4*)&scs_all[s0 + pc + q*4];
      ushort tmp[16];
      float z = 0.f;
#pragma unroll
      for (int k = 0; k < 16; ++k) {
        const int sg = s0 + pc + k;
        float pe = 0.f;
        if (sg <= tglob) pe = __expf(st * (sv[k] - pm));
        const ushort h = f2bf(pe);
        tmp[k] = h;
        z += bf2f(h);
      }
      *(uint4*)&p[buf][prow][pc    ] = *(const uint4*)&tmp[0];
      *(uint4*)&p[buf][prow][pc + 8] = *(const uint4*)&tmp[8];
      return z;
    };

    auto loadB = [&](short8* dst, int c) {
#pragma unroll
      for (int j = 0; j < 2; ++j)
#pragma unroll
        for (int ksi = 0; ksi < 2; ++ksi)
          dst[j*2 + ksi] = *(const short8*)&valT[
              (size_t)(e0 + wn + j*16 + l15) * R_ROWS + bT + c*64 + ksi*32 + lq*8];
    };

    auto mstep = [&](int buf, const short8* bfr) {
#pragma unroll
      for (int ksi = 0; ksi < 2; ++ksi) {
        short8 af[4];
#pragma unroll
        for (int i = 0; i < 4; ++i)
          af[i] = *(const short8*)&p[buf][wm + i*16 + l15][ksi*32 + lq*8];
#pragma unroll
        for (int i = 0; i < 4; ++i)
#pragma unroll
          for (int j = 0; j < 2; ++j)
            acc[i][j] = __builtin_amdgcn_mfma_f32_16x16x32_bf16(
                af[i], bfr[j*2 + ksi], acc[i][j], 0, 0, 0);
      }
    };

    short8 bA[4], bB[4];
    // prologue: chunk 0 into p[0] + V-frags
    zp += pgen(0, 0);
    loadB(bA, 0);
    __syncthreads();

#pragma unroll 1
    for (int c = 0; c < nchunk; ++c) {
      if ((c & 1) == 0) {
        if (c + 1 < nchunk) { loadB(bB, c + 1); zp += pgen(c + 1, 1); }
        mstep(0, bA);
      } else {
        if (c + 1 < nchunk) { loadB(bA, c + 1); zp += pgen(c + 1, 0); }
        mstep(1, bB);
      }
      __syncthreads();
    }

    // Z reduce (4 partials per t-row) + normalize + store
    zsh[prow][tid & 3] = zp;
    __syncthreads();
    if (tid < 128)
      zinv[tid] = 1.0f / (zsh[tid][0] + zsh[tid][1] + zsh[tid][2] + zsh[tid][3]);
    __syncthreads();

#pragma unroll
    for (int i = 0; i < 4; ++i)
#pragma unroll
      for (int j = 0; j < 2; ++j) {
        const int nb = e0 + wn + j*16 + l15;
#pragma unroll
        for (int r = 0; r < 4; ++r) {
          const int ml = wm + i*16 + lq*4 + r;
          const float v = acc[i][j][r] * zinv[ml];
          attnN[(size_t)(bT + t0 + ml) * E_DIM + nb] = f2bf(v);
        }
      }
    __syncthreads();   // zsh/zinv safe before next phase
  }
}

// ---------------------------------------------------------------------------
extern "C" void kernel_launch(void* const* d_in, const int* in_sizes, int n_in,
                              void* d_out, int out_size, void* d_ws, size_t ws_size,
                              hipStream_t stream) {
  (void)in_sizes; (void)n_in; (void)out_size; (void)ws_size;
  const float* x   = (const float*)d_in[0];
  const float* wj  = (const float*)d_in[1];
  const float* wjv = (const float*)d_in[2];
  const float* wo  = (const float*)d_in[3];
  float* out = (float*)d_out;

  ushort* xh    = (ushort*)d_ws;                        // 16 MB
  ushort* xl    = xh    + (size_t)R_ROWS * E_DIM;       // 16 MB (aliased by attnN)
  ushort* wjh   = xl    + (size_t)R_ROWS * E_DIM;       // 2 MB
  ushort* wjl   = wjh   + (size_t)E_DIM * E_DIM;        // 2 MB
  ushort* wjvb  = wjl   + (size_t)E_DIM * E_DIM;        // 2 MB
  ushort* wob   = wjvb  + (size_t)E_DIM * E_DIM;        // 2 MB
  ushort* valT  = wob   + (size_t)E_DIM * E_DIM;        // 16 MB  [E][R]
  float* sc_raw = (float*)(valT + (size_t)E_DIM * R_ROWS);
  float* sc     = sc_raw + R_ROWS;
  float* pmax   = sc + R_ROWS;
  ushort* attnN = xl;   // xl dead after gemm_sq_split (stream-serial)

  hipMemsetAsync(sc_raw, 0, R_ROWS * sizeof(float), stream);

  cvt_split<<<R_ROWS*E_DIM/4/256, 256, 0, stream>>>(x,  xh,  xl,  R_ROWS*E_DIM/4);
  cvt_split<<<E_DIM*E_DIM/4/256, 256, 0, stream>>>(wj, wjh, wjl, E_DIM*E_DIM/4);
  cvt_bf16<<<E_DIM*E_DIM/4/256, 256, 0, stream>>>(wjv, wjvb, E_DIM*E_DIM/4);
  cvt_bf16<<<E_DIM*E_DIM/4/256, 256, 0, stream>>>(wo,  wob,  E_DIM*E_DIM/4);

  // sc_raw[r] = ||x_r @ wj^T||^2  via split-bf16 MFMA (fp32-grade accuracy)
  gemm_sq_split<<<dim3(E_DIM/128, R_ROWS/128), 256, 0, stream>>>(
      xh, xl, wjh, wjl, sc_raw);
  scan_max<<<4, 1024, 0, stream>>>(sc_raw, sc, pmax);

  // valT[e][r] = sum_k wjv[e][k] * x[r][k]   (bf16 MFMA, M=1024 N=8192)
  gemm_bf16<true><<<dim3(R_ROWS/128, E_DIM/128), 256, 0, stream>>>(
      wjvb, xh, valT, E_DIM, R_ROWS, E_DIM);

  // normalized attention output, bf16  (paired t-tiles: grid 8x8x4 = 256)
  attn_mfma<<<dim3(E_DIM/128, 8, 4), 512, 0, stream>>>(valT, sc, pmax, attnN);

  // out = attnN @ wo^T   (bf16 MFMA, fp32 out, M=8192 N=1024)
  gemm_bf16<false><<<dim3(E_DIM/128, R_ROWS/128), 256, 0, stream>>>(
      attnN, wob, out, R_ROWS, E_DIM, E_DIM);
}

// Round 5
// 271.757 us; speedup vs baseline: 4.0403x; 1.0223x over previous
//
#include <hip/hip_runtime.h>
#include <math.h>

// B=4, T=2048, E=1024, H*D=1024; R = B*T = 8192.  K is always 1024.
#define R_ROWS 8192
#define T_SEQ  2048
#define E_DIM  1024
#define KC     32          // K/32 chunks

typedef __attribute__((ext_vector_type(8))) short short8;
typedef __attribute__((ext_vector_type(4))) float f32x4;

__device__ __forceinline__ ushort f2bf(float f) {
  uint u = __float_as_uint(f);
  u += 0x7FFFu + ((u >> 16) & 1u);   // round-to-nearest-even
  return (ushort)(u >> 16);
}
__device__ __forceinline__ float bf2f(ushort h) {
  return __uint_as_float(((uint)h) << 16);
}

// ---------------------------------------------------------------------------
// MFMA A/B fragment layout for a [R][1024] bf16 matrix:
//   off(r,k) = (((r>>4)*KC + (k>>5))*4 + ((k>>3)&3))*128 + (r&15)*8 + (k&7)
// A wave reading one 16-row x 32-k fragment = 64 lanes x 16B contiguous.
// ---------------------------------------------------------------------------

// fp32 [R][1024] -> (hi, lo) bf16 fragment layout. One thread = one 16B chunk.
__global__ __launch_bounds__(256) void cvt_split_frag(
    const float* __restrict__ in, ushort* __restrict__ hi,
    ushort* __restrict__ lo, int n)
{
  int g = blockIdx.x * 256 + threadIdx.x;
  if (g >= n) return;
  const int l = g & 15, h = (g >> 4) & 3;
  const int pq = g >> 6;
  const int q = pq & (KC - 1), p = pq >> 5;
  const size_t src = (size_t)(p * 16 + l) * 1024 + q * 32 + h * 8;
  const float4 v0 = *(const float4*)&in[src];
  const float4 v1 = *(const float4*)&in[src + 4];
  ushort hh[8], ll[8];
  const float v[8] = {v0.x, v0.y, v0.z, v0.w, v1.x, v1.y, v1.z, v1.w};
#pragma unroll
  for (int e = 0; e < 8; ++e) {
    hh[e] = f2bf(v[e]);
    ll[e] = f2bf(v[e] - bf2f(hh[e]));
  }
  *(uint4*)&hi[(size_t)g * 8] = *(const uint4*)hh;
  *(uint4*)&lo[(size_t)g * 8] = *(const uint4*)ll;
}

// fp32 [R][1024] -> bf16 fragment layout (single output).
__global__ __launch_bounds__(256) void cvt_bf16_frag(
    const float* __restrict__ in, ushort* __restrict__ out, int n)
{
  int g = blockIdx.x * 256 + threadIdx.x;
  if (g >= n) return;
  const int l = g & 15, h = (g >> 4) & 3;
  const int pq = g >> 6;
  const int q = pq & (KC - 1), p = pq >> 5;
  const size_t src = (size_t)(p * 16 + l) * 1024 + q * 32 + h * 8;
  const float4 v0 = *(const float4*)&in[src];
  const float4 v1 = *(const float4*)&in[src + 4];
  ushort hh[8];
  const float v[8] = {v0.x, v0.y, v0.z, v0.w, v1.x, v1.y, v1.z, v1.w};
#pragma unroll
  for (int e = 0; e < 8; ++e) hh[e] = f2bf(v[e]);
  *(uint4*)&out[(size_t)g * 8] = *(const uint4*)hh;
}

// fp32 -> bf16 row-major (for wjv, which is LDS-staged as A-operand).
__global__ __launch_bounds__(256) void cvt_bf16(
    const float* __restrict__ in, ushort* __restrict__ out, int n4)
{
  int i = blockIdx.x * 256 + threadIdx.x;
  if (i >= n4) return;
  float4 v = ((const float4*)in)[i];
  ushort4 o;
  o.x = f2bf(v.x); o.y = f2bf(v.y); o.z = f2bf(v.z); o.w = f2bf(v.w);
  ((ushort4*)out)[i] = o;
}

// ---------------------------------------------------------------------------
// Split-bf16 sc kernel, LDS-FREE K-loop: all fragments loaded directly from
// global (pre-swizzled frag layout), double-buffered in registers. No
// barriers until the epilogue. 128x128 tile, 4 waves (64x64 each), 48 MFMA
// per 32-k chunk:  echo = xh*wh + xh*wl + xl*wh;  sc_raw[m] += sum_n echo^2.
// ---------------------------------------------------------------------------
struct Frags { short8 ah[4], al[4], bh[4], bl[4]; };

__global__ __launch_bounds__(256, 2) void gemm_sq_direct(
    const ushort* __restrict__ xh, const ushort* __restrict__ xl,
    const ushort* __restrict__ wh, const ushort* __restrict__ wl,
    float* __restrict__ sc_raw)
{
  const int tid = threadIdx.x;
  const int m0 = blockIdx.y * 128, n0 = blockIdx.x * 128;
  const int wave = tid >> 6, lane = tid & 63;
  const int l15 = lane & 15, lq = lane >> 4;
  const int wm = (wave & 1) * 64, wn = (wave >> 1) * 64;

  size_t aoff[4], boff[4];
#pragma unroll
  for (int i = 0; i < 4; ++i)
    aoff[i] = ((size_t)(((m0 + wm) >> 4) + i) * KC * 4 + lq) * 128 + l15 * 8;
#pragma unroll
  for (int j = 0; j < 4; ++j)
    boff[j] = ((size_t)(((n0 + wn) >> 4) + j) * KC * 4 + lq) * 128 + l15 * 8;

  f32x4 acc[4][4] = {};
  Frags f0, f1;

  auto load = [&](Frags& f, int q) {
    const size_t dq = (size_t)q * 512;
#pragma unroll
    for (int i = 0; i < 4; ++i) {
      f.ah[i] = *(const short8*)(xh + aoff[i] + dq);
      f.al[i] = *(const short8*)(xl + aoff[i] + dq);
    }
#pragma unroll
    for (int j = 0; j < 4; ++j) {
      f.bh[j] = *(const short8*)(wh + boff[j] + dq);
      f.bl[j] = *(const short8*)(wl + boff[j] + dq);
    }
  };
  auto step = [&](const Frags& f) {
#pragma unroll
    for (int i = 0; i < 4; ++i)
#pragma unroll
      for (int j = 0; j < 4; ++j) {
        acc[i][j] = __builtin_amdgcn_mfma_f32_16x16x32_bf16(f.ah[i], f.bh[j], acc[i][j], 0, 0, 0);
        acc[i][j] = __builtin_amdgcn_mfma_f32_16x16x32_bf16(f.ah[i], f.bl[j], acc[i][j], 0, 0, 0);
        acc[i][j] = __builtin_amdgcn_mfma_f32_16x16x32_bf16(f.al[i], f.bh[j], acc[i][j], 0, 0, 0);
      }
  };

  load(f0, 0);
#pragma unroll 1
  for (int q = 0; q < KC; q += 2) {
    load(f1, q + 1);
    step(f0);
    if (q + 2 < KC) load(f0, q + 2);
    step(f1);
  }

  // Epilogue: per-row sum of squares over the 128 n-cols of this block.
  __shared__ float red[128][33];   // 16.9 KB, only used here
#pragma unroll
  for (int i = 0; i < 4; ++i)
#pragma unroll
    for (int r = 0; r < 4; ++r) {
      const int row = wm + i * 16 + lq * 4 + r;   // C/D: row = lq*4+reg
      float s = 0.f;
#pragma unroll
      for (int j = 0; j < 4; ++j) s += acc[i][j][r] * acc[i][j][r];
      red[row][(l15 << 1) | (wave >> 1)] = s;
    }
  __syncthreads();
  if (tid < 128) {
    float s = 0.f;
#pragma unroll
    for (int c = 0; c < 32; ++c) s += red[tid][c];
    atomicAdd(&sc_raw[m0 + tid], s);
  }
}

// ---------------------------------------------------------------------------
// sc = sc_raw/32; pmax = inclusive prefix max per batch (sc >= 0 always).
// ---------------------------------------------------------------------------
__global__ __launch_bounds__(1024) void scan_max(
    const float* __restrict__ sc_raw, float* __restrict__ sc,
    float* __restrict__ pmax)
{
  const int b = blockIdx.x;
  __shared__ float b0[T_SEQ];
  __shared__ float b1[T_SEQ];
  const int tid = threadIdx.x;
  for (int i = tid; i < T_SEQ; i += 1024) {
    const float v = sc_raw[b*T_SEQ + i] * 0.03125f;
    b0[i] = v;
    sc[b*T_SEQ + i] = v;
  }
  __syncthreads();
  float* src = b0; float* dst = b1;
  for (int off = 1; off < T_SEQ; off <<= 1) {
    for (int i = tid; i < T_SEQ; i += 1024)
      dst[i] = (i >= off) ? fmaxf(src[i], src[i - off]) : src[i];
    __syncthreads();
    float* tmp = src; src = dst; dst = tmp;
  }
  for (int i = tid; i < T_SEQ; i += 1024) pmax[b*T_SEQ + i] = src[i];
}

// ---------------------------------------------------------------------------
// bf16 MFMA NT GEMM, B-side direct from fragment layout (no Bs staging):
//   C[m][n] = sum_k A[m][k] * B[n][k];  A row-major (LDS-staged), Bf frag.
// ---------------------------------------------------------------------------
template<bool OUT_BF16>
__global__ __launch_bounds__(256) void gemm_bf16_bfrag(
    const ushort* __restrict__ A, const ushort* __restrict__ Bf,
    void* __restrict__ Cout, int N, int K)
{
  __shared__ ushort As[128][40];
  const int tid = threadIdx.x;
  const int m0 = blockIdx.y * 128, n0 = blockIdx.x * 128;
  const int wave = tid >> 6, lane = tid & 63;
  const int l15 = lane & 15, lq = lane >> 4;
  const int wm = (wave & 1) * 64, wn = (wave >> 1) * 64;
  const int srow = tid >> 2, scol = (tid & 3) * 8;
  const int Kc = K >> 5;

  f32x4 acc[4][4] = {};
  const ushort* Ap = A + (size_t)(m0 + srow) * K + scol;
  size_t boff[4];
#pragma unroll
  for (int j = 0; j < 4; ++j)
    boff[j] = ((size_t)(((n0 + wn) >> 4) + j) * Kc * 4 + lq) * 128 + l15 * 8;

  for (int q = 0; q < Kc; ++q) {
    const uint4 a0 = *(const uint4*)(Ap + q * 32);
    const uint4 a1 = *(const uint4*)(Ap + (size_t)64 * K + q * 32);
    short8 bfr[4];
#pragma unroll
    for (int j = 0; j < 4; ++j)
      bfr[j] = *(const short8*)(Bf + boff[j] + (size_t)q * 512);
    __syncthreads();
    *(uint4*)&As[srow     ][scol] = a0;
    *(uint4*)&As[srow + 64][scol] = a1;
    __syncthreads();
    short8 af[4];
#pragma unroll
    for (int i = 0; i < 4; ++i)
      af[i] = *(const short8*)&As[wm + i*16 + l15][lq*8];
#pragma unroll
    for (int i = 0; i < 4; ++i)
#pragma unroll
      for (int j = 0; j < 4; ++j)
        acc[i][j] = __builtin_amdgcn_mfma_f32_16x16x32_bf16(af[i], bfr[j], acc[i][j], 0, 0, 0);
  }

#pragma unroll
  for (int i = 0; i < 4; ++i)
#pragma unroll
    for (int j = 0; j < 4; ++j) {
      const int mb = m0 + wm + i*16 + lq*4;
      const int nb = n0 + wn + j*16 + l15;
#pragma unroll
      for (int r = 0; r < 4; ++r) {
        if (OUT_BF16)
          ((ushort*)Cout)[(size_t)(mb + r) * N + nb] = f2bf(acc[i][j][r]);
        else
          ((float*)Cout)[(size_t)(mb + r) * N + nb] = acc[i][j][r];
      }
    }
}

// ---------------------------------------------------------------------------
// Fused causal rank-1 attention (unchanged from round 4).
// ---------------------------------------------------------------------------
__global__ __launch_bounds__(512) void attn_mfma(
    const ushort* __restrict__ valT, const float* __restrict__ sc,
    const float* __restrict__ pmax, ushort* __restrict__ attnN)
{
  __shared__ float scs_all[T_SEQ];
  __shared__ ushort p[2][128][72];
  __shared__ float zsh[128][4];
  __shared__ float zinv[128];

  const int b  = blockIdx.z;
  const int e0 = blockIdx.x * 128;
  const int tid = threadIdx.x;
  const int wave = tid >> 6, lane = tid & 63;
  const int l15 = lane & 15, lq = lane >> 4;
  const int wm = (wave & 1) * 64;
  const int wn = (wave >> 1) * 32;
  const int bT = b * T_SEQ;

  *(float4*)&scs_all[tid * 4] = *(const float4*)&sc[bT + tid * 4];
  __syncthreads();

  const int prow = tid >> 2;
  const int pc = (tid & 3) * 16;

#pragma unroll 1
  for (int ph = 0; ph < 2; ++ph) {
    const int ty = ph == 0 ? (15 - (int)blockIdx.y) : (int)blockIdx.y;
    const int t0 = ty * 128;
    const int nchunk = 2 * ty + 2;

    const int tglob = t0 + prow;
    const float st = sc[bT + tglob];
    const float pm = pmax[bT + tglob];

    f32x4 acc[4][2] = {};
    float zp = 0.f;

    auto pgen = [&](int c, int buf) -> float {
      const int s0 = c * 64;
      float sv[16];
#pragma unroll
      for (int q = 0; q < 4; ++q)
        *(float4*)&sv[q*4] = *(const float4*)&scs_all[s0 + pc + q*4];
      ushort tmp[16];
      float z = 0.f;
#pragma unroll
      for (int k = 0; k < 16; ++k) {
        const int sg = s0 + pc + k;
        float pe = 0.f;
        if (sg <= tglob) pe = __expf(st * (sv[k] - pm));
        const ushort h = f2bf(pe);
        tmp[k] = h;
        z += bf2f(h);
      }
      *(uint4*)&p[buf][prow][pc    ] = *(const uint4*)&tmp[0];
      *(uint4*)&p[buf][prow][pc + 8] = *(const uint4*)&tmp[8];
      return z;
    };

    auto loadB = [&](short8* dst, int c) {
#pragma unroll
      for (int j = 0; j < 2; ++j)
#pragma unroll
        for (int ksi = 0; ksi < 2; ++ksi)
          dst[j*2 + ksi] = *(const short8*)&valT[
              (size_t)(e0 + wn + j*16 + l15) * R_ROWS + bT + c*64 + ksi*32 + lq*8];
    };

    auto mstep = [&](int buf, const short8* bfr) {
#pragma unroll
      for (int ksi = 0; ksi < 2; ++ksi) {
        short8 af[4];
#pragma unroll
        for (int i = 0; i < 4; ++i)
          af[i] = *(const short8*)&p[buf][wm + i*16 + l15][ksi*32 + lq*8];
#pragma unroll
        for (int i = 0; i < 4; ++i)
#pragma unroll
          for (int j = 0; j < 2; ++j)
            acc[i][j] = __builtin_amdgcn_mfma_f32_16x16x32_bf16(
                af[i], bfr[j*2 + ksi], acc[i][j], 0, 0, 0);
      }
    };

    short8 bA[4], bB[4];
    zp += pgen(0, 0);
    loadB(bA, 0);
    __syncthreads();

#pragma unroll 1
    for (int c = 0; c < nchunk; ++c) {
      if ((c & 1) == 0) {
        if (c + 1 < nchunk) { loadB(bB, c + 1); zp += pgen(c + 1, 1); }
        mstep(0, bA);
      } else {
        if (c + 1 < nchunk) { loadB(bA, c + 1); zp += pgen(c + 1, 0); }
        mstep(1, bB);
      }
      __syncthreads();
    }

    zsh[prow][tid & 3] = zp;
    __syncthreads();
    if (tid < 128)
      zinv[tid] = 1.0f / (zsh[tid][0] + zsh[tid][1] + zsh[tid][2] + zsh[tid][3]);
    __syncthreads();

#pragma unroll
    for (int i = 0; i < 4; ++i)
#pragma unroll
      for (int j = 0; j < 2; ++j) {
        const int nb = e0 + wn + j*16 + l15;
#pragma unroll
        for (int r = 0; r < 4; ++r) {
          const int ml = wm + i*16 + lq*4 + r;
          const float v = acc[i][j][r] * zinv[ml];
          attnN[(size_t)(bT + t0 + ml) * E_DIM + nb] = f2bf(v);
        }
      }
    __syncthreads();
  }
}

// ---------------------------------------------------------------------------
extern "C" void kernel_launch(void* const* d_in, const int* in_sizes, int n_in,
                              void* d_out, int out_size, void* d_ws, size_t ws_size,
                              hipStream_t stream) {
  (void)in_sizes; (void)n_in; (void)out_size; (void)ws_size;
  const float* x   = (const float*)d_in[0];
  const float* wj  = (const float*)d_in[1];
  const float* wjv = (const float*)d_in[2];
  const float* wo  = (const float*)d_in[3];
  float* out = (float*)d_out;

  ushort* xh_f  = (ushort*)d_ws;                        // 16 MB frag
  ushort* xl_f  = xh_f  + (size_t)R_ROWS * E_DIM;       // 16 MB frag
  ushort* wjh_f = xl_f  + (size_t)R_ROWS * E_DIM;       // 2 MB frag
  ushort* wjl_f = wjh_f + (size_t)E_DIM * E_DIM;        // 2 MB frag
  ushort* wjvb  = wjl_f + (size_t)E_DIM * E_DIM;        // 2 MB row-major
  ushort* wob_f = wjvb  + (size_t)E_DIM * E_DIM;        // 2 MB frag
  float* sc_raw = (float*)(wob_f + (size_t)E_DIM * E_DIM);
  float* sc     = sc_raw + R_ROWS;
  float* pmax   = sc + R_ROWS;
  ushort* valT  = xl_f;   // xl_f dead after gemm_sq_direct (stream-serial)
  ushort* attnN = xh_f;   // xh_f dead after the val GEMM

  hipMemsetAsync(sc_raw, 0, R_ROWS * sizeof(float), stream);

  cvt_split_frag<<<R_ROWS*E_DIM/8/256, 256, 0, stream>>>(x,  xh_f,  xl_f,  R_ROWS*E_DIM/8);
  cvt_split_frag<<<E_DIM*E_DIM/8/256, 256, 0, stream>>>(wj, wjh_f, wjl_f, E_DIM*E_DIM/8);
  cvt_bf16<<<E_DIM*E_DIM/4/256, 256, 0, stream>>>(wjv, wjvb, E_DIM*E_DIM/4);
  cvt_bf16_frag<<<E_DIM*E_DIM/8/256, 256, 0, stream>>>(wo, wob_f, E_DIM*E_DIM/8);

  // sc_raw[r] = ||x_r @ wj^T||^2  (split-bf16 MFMA, LDS-free direct frags)
  gemm_sq_direct<<<dim3(E_DIM/128, R_ROWS/128), 256, 0, stream>>>(
      xh_f, xl_f, wjh_f, wjl_f, sc_raw);
  scan_max<<<4, 1024, 0, stream>>>(sc_raw, sc, pmax);

  // valT[e][r] = sum_k wjv[e][k] * x[r][k]   (A staged, B=x frag-direct)
  gemm_bf16_bfrag<true><<<dim3(R_ROWS/128, E_DIM/128), 256, 0, stream>>>(
      wjvb, xh_f, valT, R_ROWS, E_DIM);

  // normalized attention output, bf16  (paired t-tiles: grid 8x8x4 = 256)
  attn_mfma<<<dim3(E_DIM/128, 8, 4), 512, 0, stream>>>(valT, sc, pmax, attnN);

  // out = attnN @ wo^T   (A staged, B=wo frag-direct, fp32 out)
  gemm_bf16_bfrag<false><<<dim3(E_DIM/128, R_ROWS/128), 256, 0, stream>>>(
      attnN, wob_f, out, E_DIM, E_DIM);
}